// Round 1
// baseline (804.421 us; speedup 1.0000x reference)
//
#include <hip/hip_runtime.h>
#include <math.h>

#define NN 50000
#define E0 800000
#define ET 850000

// ---------------- CSR build ----------------

__global__ void zero_int_kernel(int* __restrict__ p, int n) {
  int i = blockIdx.x * blockDim.x + threadIdx.x;
  if (i < n) p[i] = 0;
}

__global__ void count_kernel(const int* __restrict__ ei, int* __restrict__ cnt) {
  int e = blockIdx.x * blockDim.x + threadIdx.x;
  if (e >= ET) return;
  int dst = (e < E0) ? ei[E0 + e] : (e - E0);
  atomicAdd(&cnt[dst], 1);
}

__global__ __launch_bounds__(1024) void scan_kernel(const int* __restrict__ cnt,
                                                    int* __restrict__ rowptr) {
  __shared__ int sdata[1024];
  __shared__ int carry_s;
  if (threadIdx.x == 0) carry_s = 0;
  __syncthreads();
  for (int base = 0; base < NN; base += 1024) {
    int i = base + (int)threadIdx.x;
    int v = (i < NN) ? cnt[i] : 0;
    int val = v;
    sdata[threadIdx.x] = val;
    __syncthreads();
    for (int off = 1; off < 1024; off <<= 1) {
      int t = (threadIdx.x >= (unsigned)off) ? sdata[threadIdx.x - off] : 0;
      __syncthreads();
      val += t;
      sdata[threadIdx.x] = val;
      __syncthreads();
    }
    int run = carry_s;
    if (i < NN) rowptr[i] = run + val - v;  // exclusive scan
    __syncthreads();
    if (threadIdx.x == 1023) carry_s = run + sdata[1023];
    __syncthreads();
  }
  if (threadIdx.x == 0) rowptr[NN] = carry_s;
}

__global__ void scatter_kernel(const int* __restrict__ ei, const int* __restrict__ rowptr,
                               int* __restrict__ cursor, int* __restrict__ csr_src) {
  int e = blockIdx.x * blockDim.x + threadIdx.x;
  if (e >= ET) return;
  int src, dst;
  if (e < E0) { src = ei[e]; dst = ei[E0 + e]; }
  else        { src = e - E0; dst = src; }
  int pos = rowptr[dst] + atomicAdd(&cursor[dst], 1);
  csr_src[pos] = src;
}

// ---------------- GEMM (X @ W) + per-node attention logits ----------------
// X:[N,128] W:[128,128] -> hfeat:[N,128], es/ed:[N,2]
// block = 256 threads computes a 128-node x 128-col tile; 8x8 register tile.
__global__ __launch_bounds__(256) void gemm_att_kernel(
    const float* __restrict__ X, const float* __restrict__ W,
    const float* __restrict__ avs, const float* __restrict__ avd,
    float* __restrict__ hfeat, float* __restrict__ es, float* __restrict__ ed,
    int nnodes)
{
  __shared__ float Ws[32][128];    // k-tile of W
  __shared__ float XsT[32][136];   // transposed X tile, padded
  __shared__ float es_s[2][128];
  __shared__ float ed_s[2][128];
  const int tid = threadIdx.x;
  const int n0 = blockIdx.x * 128;
  const int rr = tid & 15, cc = tid >> 4;
  const int r0 = rr * 8, j0 = cc * 8;
  if (tid < 128) { es_s[0][tid] = 0.f; es_s[1][tid] = 0.f; ed_s[0][tid] = 0.f; ed_s[1][tid] = 0.f; }
  float acc[8][8];
#pragma unroll
  for (int i = 0; i < 8; i++)
#pragma unroll
    for (int j = 0; j < 8; j++) acc[i][j] = 0.f;

  for (int kt = 0; kt < 128; kt += 32) {
    __syncthreads();
#pragma unroll
    for (int i = 0; i < 4; ++i) {       // W tile: 1024 float4
      int q = tid + 256 * i;
      int k = q >> 5, j = (q & 31) * 4;
      float4 wv = *(const float4*)&W[(kt + k) * 128 + j];
      *(float4*)&Ws[k][j] = wv;
    }
#pragma unroll
    for (int i = 0; i < 4; ++i) {       // X tile (transposed into LDS)
      int q = tid + 256 * i;
      int r = q >> 3, kk = (q & 7) * 4;
      float4 xv = make_float4(0.f, 0.f, 0.f, 0.f);
      if (n0 + r < nnodes) xv = *(const float4*)&X[(size_t)(n0 + r) * 128 + kt + kk];
      XsT[kk + 0][r] = xv.x; XsT[kk + 1][r] = xv.y;
      XsT[kk + 2][r] = xv.z; XsT[kk + 3][r] = xv.w;
    }
    __syncthreads();
#pragma unroll
    for (int k = 0; k < 32; ++k) {
      float4 xa = *(const float4*)&XsT[k][r0];
      float4 xb = *(const float4*)&XsT[k][r0 + 4];
      float4 wa = *(const float4*)&Ws[k][j0];
      float4 wb = *(const float4*)&Ws[k][j0 + 4];
      float xs[8] = {xa.x, xa.y, xa.z, xa.w, xb.x, xb.y, xb.z, xb.w};
      float wv[8] = {wa.x, wa.y, wa.z, wa.w, wb.x, wb.y, wb.z, wb.w};
#pragma unroll
      for (int i = 0; i < 8; i++)
#pragma unroll
        for (int j = 0; j < 8; j++) acc[i][j] += xs[i] * wv[j];
    }
  }
  // attention partials + hfeat store
  float as_[8], ad_[8];
#pragma unroll
  for (int j = 0; j < 8; j++) { as_[j] = avs[j0 + j]; ad_[j] = avd[j0 + j]; }
  const int head = (j0 >= 64) ? 1 : 0;
#pragma unroll
  for (int i = 0; i < 8; i++) {
    int n = n0 + r0 + i;
    float ps = 0.f, pd = 0.f;
#pragma unroll
    for (int j = 0; j < 8; j++) { ps += acc[i][j] * as_[j]; pd += acc[i][j] * ad_[j]; }
    atomicAdd(&es_s[head][r0 + i], ps);
    atomicAdd(&ed_s[head][r0 + i], pd);
    if (n < nnodes) {
      float4 v0 = make_float4(acc[i][0], acc[i][1], acc[i][2], acc[i][3]);
      float4 v1 = make_float4(acc[i][4], acc[i][5], acc[i][6], acc[i][7]);
      *(float4*)&hfeat[(size_t)n * 128 + j0] = v0;
      *(float4*)&hfeat[(size_t)n * 128 + j0 + 4] = v1;
    }
  }
  __syncthreads();
  if (tid < 128) {
    int n = n0 + tid;
    if (n < nnodes) {
      es[n * 2 + 0] = es_s[0][tid]; es[n * 2 + 1] = es_s[1][tid];
      ed[n * 2 + 0] = ed_s[0][tid]; ed[n * 2 + 1] = ed_s[1][tid];
    }
  }
}

// ---------------- edge-softmax + aggregation (one wave per (node, head)) ----------------
// alpha = exp(e)/sum(exp(e)) (max-subtraction-free; self-loop guarantees denom>0)
__global__ __launch_bounds__(256) void aggregate_kernel(
    const float* __restrict__ hfeat, const float* __restrict__ es, const float* __restrict__ ed,
    const int* __restrict__ rowptr, const int* __restrict__ csr_src,
    const float* __restrict__ bias, float* __restrict__ out, int nnodes)
{
  int wid = (blockIdx.x * blockDim.x + threadIdx.x) >> 6;
  int lane = threadIdx.x & 63;
  int n = wid >> 1, h = wid & 1;
  if (n >= nnodes) return;
  int beg = rowptr[n], end = rowptr[n + 1];
  float edn = ed[n * 2 + h];
  float acc = 0.f, denom = 0.f;
  int i = beg;
  for (; i + 2 <= end; i += 2) {
    int s0 = csr_src[i], s1 = csr_src[i + 1];
    float e0v = es[s0 * 2 + h] + edn;
    float e1v = es[s1 * 2 + h] + edn;
    float hv0 = hfeat[(size_t)s0 * 128 + h * 64 + lane];
    float hv1 = hfeat[(size_t)s1 * 128 + h * 64 + lane];
    e0v = (e0v > 0.f) ? e0v : 0.2f * e0v;
    e1v = (e1v > 0.f) ? e1v : 0.2f * e1v;
    float w0 = __expf(e0v), w1 = __expf(e1v);
    denom += w0 + w1;
    acc += w0 * hv0 + w1 * hv1;
  }
  if (i < end) {
    int s0 = csr_src[i];
    float e0v = es[s0 * 2 + h] + edn;
    float hv0 = hfeat[(size_t)s0 * 128 + h * 64 + lane];
    e0v = (e0v > 0.f) ? e0v : 0.2f * e0v;
    float w0 = __expf(e0v);
    denom += w0; acc += w0 * hv0;
  }
  float v = acc / denom + bias[h * 64 + lane];
  out[(size_t)n * 128 + h * 64 + lane] = (v > 0.f) ? v : (__expf(v) - 1.f);  // ELU
}

// ---------------- final linear (256->40) + log_softmax ----------------
__global__ __launch_bounds__(256) void final_kernel(
    const float* __restrict__ h1, const float* __restrict__ h2,
    const float* __restrict__ lw, const float* __restrict__ lb,
    float* __restrict__ out, int nnodes)
{
  __shared__ float Wl[256 * 40 + 64];
  for (int i = threadIdx.x; i < 256 * 40; i += 256) Wl[i] = lw[i];
  for (int i = 256 * 40 + threadIdx.x; i < 256 * 40 + 64; i += 256) Wl[i] = 0.f;
  __syncthreads();
  int lane = threadIdx.x & 63;
  int wv = threadIdx.x >> 6;
  int nbase = (blockIdx.x * 4 + wv) * 16;
  float bj = (lane < 40) ? lb[lane] : 0.f;
  for (int t = 0; t < 16; ++t) {
    int n = nbase + t;
    if (n >= nnodes) return;
    float hr0 = h1[(size_t)n * 128 + lane];
    float hr1 = h1[(size_t)n * 128 + 64 + lane];
    float hr2 = h2[(size_t)n * 128 + lane];
    float hr3 = h2[(size_t)n * 128 + 64 + lane];
    float accv = bj;
#pragma unroll 8
    for (int k = 0; k < 64; ++k) {
      float v0 = __shfl(hr0, k);
      float v1 = __shfl(hr1, k);
      float v2 = __shfl(hr2, k);
      float v3 = __shfl(hr3, k);
      accv += v0 * Wl[k * 40 + lane] + v1 * Wl[(64 + k) * 40 + lane]
            + v2 * Wl[(128 + k) * 40 + lane] + v3 * Wl[(192 + k) * 40 + lane];
    }
    float v = (lane < 40) ? accv : -INFINITY;
    float m = v;
#pragma unroll
    for (int off = 32; off > 0; off >>= 1) m = fmaxf(m, __shfl_xor(m, off));
    float exv = (lane < 40) ? __expf(v - m) : 0.f;
    float s = exv;
#pragma unroll
    for (int off = 32; off > 0; off >>= 1) s += __shfl_xor(s, off);
    if (lane < 40) out[(size_t)n * 40 + lane] = v - m - __logf(s);
  }
}

// ---------------- launch ----------------

extern "C" void kernel_launch(void* const* d_in, const int* in_sizes, int n_in,
                              void* d_out, int out_size, void* d_ws, size_t ws_size,
                              hipStream_t stream) {
  const float* x   = (const float*)d_in[0];
  const int*   ei  = (const int*)d_in[1];
  const float* W0  = (const float*)d_in[2];
  const float* as0 = (const float*)d_in[3];
  const float* ad0 = (const float*)d_in[4];
  const float* b0  = (const float*)d_in[5];
  const float* W1  = (const float*)d_in[6];
  const float* as1 = (const float*)d_in[7];
  const float* ad1 = (const float*)d_in[8];
  const float* b1  = (const float*)d_in[9];
  const float* lw  = (const float*)d_in[10];
  const float* lb  = (const float*)d_in[11];
  float* out = (float*)d_out;

  char* p = (char*)d_ws;
  auto carve = [&](size_t bytes) { char* r = p; p += (bytes + 255) & ~(size_t)255; return r; };
  float* hfeat = (float*)carve((size_t)NN * 128 * 4);
  float* h1o   = (float*)carve((size_t)NN * 128 * 4);
  float* h2o   = (float*)carve((size_t)NN * 128 * 4);
  float* es    = (float*)carve((size_t)NN * 2 * 4);
  float* ed    = (float*)carve((size_t)NN * 2 * 4);
  int* rowptr  = (int*)carve((size_t)(NN + 1) * 4);
  int* cnt     = (int*)carve((size_t)NN * 4);
  int* csr     = (int*)carve((size_t)ET * 4);

  // CSR build (reused by both layers)
  zero_int_kernel<<<(NN + 1023) / 1024, 1024, 0, stream>>>(cnt, NN);
  count_kernel<<<(ET + 255) / 256, 256, 0, stream>>>(ei, cnt);
  scan_kernel<<<1, 1024, 0, stream>>>(cnt, rowptr);
  zero_int_kernel<<<(NN + 1023) / 1024, 1024, 0, stream>>>(cnt, NN);
  scatter_kernel<<<(ET + 255) / 256, 256, 0, stream>>>(ei, rowptr, cnt, csr);

  // layer 1
  gemm_att_kernel<<<(NN + 127) / 128, 256, 0, stream>>>(x, W0, as0, ad0, hfeat, es, ed, NN);
  aggregate_kernel<<<25000, 256, 0, stream>>>(hfeat, es, ed, rowptr, csr, b0, h1o, NN);
  // layer 2
  gemm_att_kernel<<<(NN + 127) / 128, 256, 0, stream>>>(h1o, W1, as1, ad1, hfeat, es, ed, NN);
  aggregate_kernel<<<25000, 256, 0, stream>>>(hfeat, es, ed, rowptr, csr, b1, h2o, NN);
  // head
  final_kernel<<<(NN + 63) / 64, 256, 0, stream>>>(h1o, h2o, lw, lb, out, NN);
}

// Round 2
// 615.393 us; speedup vs baseline: 1.3072x; 1.3072x over previous
//
#include <hip/hip_runtime.h>
#include <math.h>

#define NN 50000
#define E0 800000
#define ET 850000

// ---------------- CSR build ----------------

__global__ void zero_int_kernel(int* __restrict__ p, int n) {
  int i = blockIdx.x * blockDim.x + threadIdx.x;
  if (i < n) p[i] = 0;
}

__global__ void count_kernel(const int* __restrict__ ei, int* __restrict__ cnt) {
  int e = blockIdx.x * blockDim.x + threadIdx.x;
  if (e >= ET) return;
  int dst = (e < E0) ? ei[E0 + e] : (e - E0);
  atomicAdd(&cnt[dst], 1);
}

__global__ __launch_bounds__(1024) void scan_kernel(const int* __restrict__ cnt,
                                                    int* __restrict__ rowptr) {
  __shared__ int sdata[1024];
  __shared__ int carry_s;
  if (threadIdx.x == 0) carry_s = 0;
  __syncthreads();
  for (int base = 0; base < NN; base += 1024) {
    int i = base + (int)threadIdx.x;
    int v = (i < NN) ? cnt[i] : 0;
    int val = v;
    sdata[threadIdx.x] = val;
    __syncthreads();
    for (int off = 1; off < 1024; off <<= 1) {
      int t = (threadIdx.x >= (unsigned)off) ? sdata[threadIdx.x - off] : 0;
      __syncthreads();
      val += t;
      sdata[threadIdx.x] = val;
      __syncthreads();
    }
    int run = carry_s;
    if (i < NN) rowptr[i] = run + val - v;  // exclusive scan
    __syncthreads();
    if (threadIdx.x == 1023) carry_s = run + sdata[1023];
    __syncthreads();
  }
  if (threadIdx.x == 0) rowptr[NN] = carry_s;
}

__global__ void scatter_kernel(const int* __restrict__ ei, const int* __restrict__ rowptr,
                               int* __restrict__ cursor, int* __restrict__ csr_src) {
  int e = blockIdx.x * blockDim.x + threadIdx.x;
  if (e >= ET) return;
  int src, dst;
  if (e < E0) { src = ei[e]; dst = ei[E0 + e]; }
  else        { src = e - E0; dst = src; }
  int pos = rowptr[dst] + atomicAdd(&cursor[dst], 1);
  csr_src[pos] = src;
}

// ---------------- GEMM (X @ W) + per-node attention logits ----------------
__global__ __launch_bounds__(256) void gemm_att_kernel(
    const float* __restrict__ X, const float* __restrict__ W,
    const float* __restrict__ avs, const float* __restrict__ avd,
    float* __restrict__ hfeat, float* __restrict__ es, float* __restrict__ ed,
    int nnodes)
{
  __shared__ float Ws[32][128];    // k-tile of W
  __shared__ float XsT[32][136];   // transposed X tile, padded
  __shared__ float es_s[2][128];
  __shared__ float ed_s[2][128];
  const int tid = threadIdx.x;
  const int n0 = blockIdx.x * 128;
  const int rr = tid & 15, cc = tid >> 4;
  const int r0 = rr * 8, j0 = cc * 8;
  if (tid < 128) { es_s[0][tid] = 0.f; es_s[1][tid] = 0.f; ed_s[0][tid] = 0.f; ed_s[1][tid] = 0.f; }
  float acc[8][8];
#pragma unroll
  for (int i = 0; i < 8; i++)
#pragma unroll
    for (int j = 0; j < 8; j++) acc[i][j] = 0.f;

  for (int kt = 0; kt < 128; kt += 32) {
    __syncthreads();
#pragma unroll
    for (int i = 0; i < 4; ++i) {       // W tile: 1024 float4
      int q = tid + 256 * i;
      int k = q >> 5, j = (q & 31) * 4;
      float4 wv = *(const float4*)&W[(kt + k) * 128 + j];
      *(float4*)&Ws[k][j] = wv;
    }
#pragma unroll
    for (int i = 0; i < 4; ++i) {       // X tile (transposed into LDS)
      int q = tid + 256 * i;
      int r = q >> 3, kk = (q & 7) * 4;
      float4 xv = make_float4(0.f, 0.f, 0.f, 0.f);
      if (n0 + r < nnodes) xv = *(const float4*)&X[(size_t)(n0 + r) * 128 + kt + kk];
      XsT[kk + 0][r] = xv.x; XsT[kk + 1][r] = xv.y;
      XsT[kk + 2][r] = xv.z; XsT[kk + 3][r] = xv.w;
    }
    __syncthreads();
#pragma unroll
    for (int k = 0; k < 32; ++k) {
      float4 xa = *(const float4*)&XsT[k][r0];
      float4 xb = *(const float4*)&XsT[k][r0 + 4];
      float4 wa = *(const float4*)&Ws[k][j0];
      float4 wb = *(const float4*)&Ws[k][j0 + 4];
      float xs[8] = {xa.x, xa.y, xa.z, xa.w, xb.x, xb.y, xb.z, xb.w};
      float wv[8] = {wa.x, wa.y, wa.z, wa.w, wb.x, wb.y, wb.z, wb.w};
#pragma unroll
      for (int i = 0; i < 8; i++)
#pragma unroll
        for (int j = 0; j < 8; j++) acc[i][j] += xs[i] * wv[j];
    }
  }
  float as_[8], ad_[8];
#pragma unroll
  for (int j = 0; j < 8; j++) { as_[j] = avs[j0 + j]; ad_[j] = avd[j0 + j]; }
  const int head = (j0 >= 64) ? 1 : 0;
#pragma unroll
  for (int i = 0; i < 8; i++) {
    int n = n0 + r0 + i;
    float ps = 0.f, pd = 0.f;
#pragma unroll
    for (int j = 0; j < 8; j++) { ps += acc[i][j] * as_[j]; pd += acc[i][j] * ad_[j]; }
    atomicAdd(&es_s[head][r0 + i], ps);
    atomicAdd(&ed_s[head][r0 + i], pd);
    if (n < nnodes) {
      float4 v0 = make_float4(acc[i][0], acc[i][1], acc[i][2], acc[i][3]);
      float4 v1 = make_float4(acc[i][4], acc[i][5], acc[i][6], acc[i][7]);
      *(float4*)&hfeat[(size_t)n * 128 + j0] = v0;
      *(float4*)&hfeat[(size_t)n * 128 + j0 + 4] = v1;
    }
  }
  __syncthreads();
  if (tid < 128) {
    int n = n0 + tid;
    if (n < nnodes) {
      es[n * 2 + 0] = es_s[0][tid]; es[n * 2 + 1] = es_s[1][tid];
      ed[n * 2 + 0] = ed_s[0][tid]; ed[n * 2 + 1] = ed_s[1][tid];
    }
  }
}

// ---------------- edge-softmax + aggregation (one wave per (node, head)) ----------------
__global__ __launch_bounds__(256) void aggregate_kernel(
    const float* __restrict__ hfeat, const float* __restrict__ es, const float* __restrict__ ed,
    const int* __restrict__ rowptr, const int* __restrict__ csr_src,
    const float* __restrict__ bias, float* __restrict__ out, int nnodes)
{
  int wid = (blockIdx.x * blockDim.x + threadIdx.x) >> 6;
  int lane = threadIdx.x & 63;
  int n = wid >> 1, h = wid & 1;
  if (n >= nnodes) return;
  int beg = rowptr[n], end = rowptr[n + 1];
  float edn = ed[n * 2 + h];
  float acc = 0.f, denom = 0.f;
  int i = beg;
  for (; i + 2 <= end; i += 2) {
    int s0 = csr_src[i], s1 = csr_src[i + 1];
    float e0v = es[s0 * 2 + h] + edn;
    float e1v = es[s1 * 2 + h] + edn;
    float hv0 = hfeat[(size_t)s0 * 128 + h * 64 + lane];
    float hv1 = hfeat[(size_t)s1 * 128 + h * 64 + lane];
    e0v = (e0v > 0.f) ? e0v : 0.2f * e0v;
    e1v = (e1v > 0.f) ? e1v : 0.2f * e1v;
    float w0 = __expf(e0v), w1 = __expf(e1v);
    denom += w0 + w1;
    acc += w0 * hv0 + w1 * hv1;
  }
  if (i < end) {
    int s0 = csr_src[i];
    float e0v = es[s0 * 2 + h] + edn;
    float hv0 = hfeat[(size_t)s0 * 128 + h * 64 + lane];
    e0v = (e0v > 0.f) ? e0v : 0.2f * e0v;
    float w0 = __expf(e0v);
    denom += w0; acc += w0 * hv0;
  }
  float v = acc / denom + bias[h * 64 + lane];
  out[(size_t)n * 128 + h * 64 + lane] = (v > 0.f) ? v : (__expf(v) - 1.f);  // ELU
}

// ---------------- final linear (256->40) + log_softmax, tiled GEMM ----------------
// Block: 256 threads, 64 nodes. Thread (m = tid>>2, q = tid&3) computes node m,
// cols q*10..q*10+9. K staged in 32-wide chunks. Softmax via quad shuffle.
__global__ __launch_bounds__(256) void final_kernel(
    const float* __restrict__ h1, const float* __restrict__ h2,
    const float* __restrict__ lw, const float* __restrict__ lb,
    float* __restrict__ out, int nnodes)
{
  __shared__ __align__(16) float Hs[64][33];
  __shared__ __align__(16) float Ws2[32 * 40];
  const int tid = threadIdx.x;
  const int m = tid >> 2, q = tid & 3;
  const int n0 = blockIdx.x * 64;

  float bj[10];
#pragma unroll
  for (int j = 0; j < 10; ++j) bj[j] = lb[q * 10 + j];

  float acc[10];
#pragma unroll
  for (int j = 0; j < 10; ++j) acc[j] = 0.f;

  for (int kc = 0; kc < 256; kc += 32) {
    __syncthreads();
    // stage Hs: 64 nodes x 32 k = 512 float4; 2 per thread
#pragma unroll
    for (int it = 0; it < 2; ++it) {
      int idx = tid + it * 256;
      int nd = idx >> 3, kk = (idx & 7) * 4;
      int n = n0 + nd;
      float4 v = make_float4(0.f, 0.f, 0.f, 0.f);
      if (n < nnodes) {
        const float* src = (kc < 128) ? &h1[(size_t)n * 128 + kc + kk]
                                      : &h2[(size_t)n * 128 + (kc - 128) + kk];
        v = *(const float4*)src;
      }
      Hs[nd][kk + 0] = v.x; Hs[nd][kk + 1] = v.y;
      Hs[nd][kk + 2] = v.z; Hs[nd][kk + 3] = v.w;
    }
    // stage W chunk: 32 rows x 40 cols = 1280 floats = 320 float4
    {
      float4 v = *(const float4*)&lw[kc * 40 + tid * 4];
      *(float4*)&Ws2[tid * 4] = v;
      if (tid < 64) {
        float4 v2 = *(const float4*)&lw[kc * 40 + (256 + tid) * 4];
        *(float4*)&Ws2[(256 + tid) * 4] = v2;
      }
    }
    __syncthreads();
#pragma unroll
    for (int k = 0; k < 32; ++k) {
      float a = Hs[m][k];
      const float* wr = &Ws2[k * 40 + q * 10];
#pragma unroll
      for (int j = 0; j < 10; ++j) acc[j] = fmaf(a, wr[j], acc[j]);
    }
  }

  // bias + log_softmax across the quad (lanes 4m..4m+3 within the wave)
  float mx = -INFINITY;
#pragma unroll
  for (int j = 0; j < 10; ++j) { acc[j] += bj[j]; mx = fmaxf(mx, acc[j]); }
  mx = fmaxf(mx, __shfl_xor(mx, 1));
  mx = fmaxf(mx, __shfl_xor(mx, 2));
  float s = 0.f;
#pragma unroll
  for (int j = 0; j < 10; ++j) s += __expf(acc[j] - mx);
  s += __shfl_xor(s, 1);
  s += __shfl_xor(s, 2);
  float lg = mx + __logf(s);
  int n = n0 + m;
  if (n < nnodes) {
#pragma unroll
    for (int j = 0; j < 10; ++j) out[(size_t)n * 40 + q * 10 + j] = acc[j] - lg;
  }
}

// ---------------- launch ----------------

extern "C" void kernel_launch(void* const* d_in, const int* in_sizes, int n_in,
                              void* d_out, int out_size, void* d_ws, size_t ws_size,
                              hipStream_t stream) {
  const float* x   = (const float*)d_in[0];
  const int*   ei  = (const int*)d_in[1];
  const float* W0  = (const float*)d_in[2];
  const float* as0 = (const float*)d_in[3];
  const float* ad0 = (const float*)d_in[4];
  const float* b0  = (const float*)d_in[5];
  const float* W1  = (const float*)d_in[6];
  const float* as1 = (const float*)d_in[7];
  const float* ad1 = (const float*)d_in[8];
  const float* b1  = (const float*)d_in[9];
  const float* lw  = (const float*)d_in[10];
  const float* lb  = (const float*)d_in[11];
  float* out = (float*)d_out;

  char* p = (char*)d_ws;
  auto carve = [&](size_t bytes) { char* r = p; p += (bytes + 255) & ~(size_t)255; return r; };
  float* hfeat = (float*)carve((size_t)NN * 128 * 4);
  float* h1o   = (float*)carve((size_t)NN * 128 * 4);
  float* h2o   = (float*)carve((size_t)NN * 128 * 4);
  float* es    = (float*)carve((size_t)NN * 2 * 4);
  float* ed    = (float*)carve((size_t)NN * 2 * 4);
  int* rowptr  = (int*)carve((size_t)(NN + 1) * 4);
  int* cnt     = (int*)carve((size_t)NN * 4);
  int* csr     = (int*)carve((size_t)ET * 4);

  // CSR build (reused by both layers)
  zero_int_kernel<<<(NN + 1023) / 1024, 1024, 0, stream>>>(cnt, NN);
  count_kernel<<<(ET + 255) / 256, 256, 0, stream>>>(ei, cnt);
  scan_kernel<<<1, 1024, 0, stream>>>(cnt, rowptr);
  zero_int_kernel<<<(NN + 1023) / 1024, 1024, 0, stream>>>(cnt, NN);
  scatter_kernel<<<(ET + 255) / 256, 256, 0, stream>>>(ei, rowptr, cnt, csr);

  // layer 1
  gemm_att_kernel<<<(NN + 127) / 128, 256, 0, stream>>>(x, W0, as0, ad0, hfeat, es, ed, NN);
  aggregate_kernel<<<25000, 256, 0, stream>>>(hfeat, es, ed, rowptr, csr, b0, h1o, NN);
  // layer 2
  gemm_att_kernel<<<(NN + 127) / 128, 256, 0, stream>>>(h1o, W1, as1, ad1, hfeat, es, ed, NN);
  aggregate_kernel<<<25000, 256, 0, stream>>>(hfeat, es, ed, rowptr, csr, b1, h2o, NN);
  // head
  final_kernel<<<(NN + 63) / 64, 256, 0, stream>>>(h1o, h2o, lw, lb, out, NN);
}

// Round 3
// 478.326 us; speedup vs baseline: 1.6817x; 1.2866x over previous
//
#include <hip/hip_runtime.h>
#include <math.h>

#define NN 50000
#define E0 800000
#define ET 850000
#define NB 196  // ceil(NN/256) scan blocks

// ---------------- CSR build ----------------

__global__ void zero_int_kernel(int* __restrict__ p, int n) {
  int i = blockIdx.x * blockDim.x + threadIdx.x;
  if (i < n) p[i] = 0;
}

__global__ void count_kernel(const int* __restrict__ ei, int* __restrict__ cnt) {
  int e = blockIdx.x * blockDim.x + threadIdx.x;
  if (e >= ET) return;
  int dst = (e < E0) ? ei[E0 + e] : (e - E0);
  atomicAdd(&cnt[dst], 1);
}

// two-level scan: L1 per-256 block scan, L2 scan of block sums, L3 add offsets
__global__ __launch_bounds__(256) void scan_l1_kernel(const int* __restrict__ cnt,
                                                      int* __restrict__ rowptr,
                                                      int* __restrict__ bsum) {
  __shared__ int s[256];
  int i = blockIdx.x * 256 + threadIdx.x;
  int v = (i < NN) ? cnt[i] : 0;
  int val = v;
  s[threadIdx.x] = val;
  __syncthreads();
#pragma unroll
  for (int off = 1; off < 256; off <<= 1) {
    int t = (threadIdx.x >= (unsigned)off) ? s[threadIdx.x - off] : 0;
    __syncthreads();
    val += t;
    s[threadIdx.x] = val;
    __syncthreads();
  }
  if (i < NN) rowptr[i] = val - v;  // block-local exclusive
  if (threadIdx.x == 255) bsum[blockIdx.x] = val;
}

__global__ __launch_bounds__(256) void scan_l2_kernel(const int* __restrict__ bsum,
                                                      int* __restrict__ boff,
                                                      int* __restrict__ rowptr) {
  __shared__ int s[256];
  int i = threadIdx.x;
  int v = (i < NB) ? bsum[i] : 0;
  int val = v;
  s[i] = val;
  __syncthreads();
#pragma unroll
  for (int off = 1; off < 256; off <<= 1) {
    int t = (i >= (unsigned)off) ? s[i - off] : 0;
    __syncthreads();
    val += t;
    s[i] = val;
    __syncthreads();
  }
  if (i < NB) boff[i] = val - v;  // exclusive
  if (i == NB - 1) rowptr[NN] = val;  // total = ET
}

__global__ __launch_bounds__(256) void scan_add_kernel(int* __restrict__ rowptr,
                                                       const int* __restrict__ boff) {
  int i = blockIdx.x * 256 + threadIdx.x;
  if (i < NN) rowptr[i] += boff[blockIdx.x];
}

__global__ void scatter_kernel(const int* __restrict__ ei, const int* __restrict__ rowptr,
                               int* __restrict__ cursor, int* __restrict__ csr_src,
                               int* __restrict__ csr_dst) {
  int e = blockIdx.x * blockDim.x + threadIdx.x;
  if (e >= ET) return;
  int src, dst;
  if (e < E0) { src = ei[e]; dst = ei[E0 + e]; }
  else        { src = e - E0; dst = src; }
  int pos = rowptr[dst] + atomicAdd(&cursor[dst], 1);
  csr_src[pos] = src;
  csr_dst[pos] = dst;
}

// ---------------- GEMM (X @ W) + per-node attention logits ----------------
__global__ __launch_bounds__(256) void gemm_att_kernel(
    const float* __restrict__ X, const float* __restrict__ W,
    const float* __restrict__ avs, const float* __restrict__ avd,
    float* __restrict__ hfeat, float* __restrict__ es, float* __restrict__ ed,
    int nnodes)
{
  __shared__ float Ws[32][128];    // k-tile of W
  __shared__ float XsT[32][136];   // transposed X tile, padded
  __shared__ float es_s[2][128];
  __shared__ float ed_s[2][128];
  const int tid = threadIdx.x;
  const int n0 = blockIdx.x * 128;
  const int rr = tid & 15, cc = tid >> 4;
  const int r0 = rr * 8, j0 = cc * 8;
  if (tid < 128) { es_s[0][tid] = 0.f; es_s[1][tid] = 0.f; ed_s[0][tid] = 0.f; ed_s[1][tid] = 0.f; }
  float acc[8][8];
#pragma unroll
  for (int i = 0; i < 8; i++)
#pragma unroll
    for (int j = 0; j < 8; j++) acc[i][j] = 0.f;

  for (int kt = 0; kt < 128; kt += 32) {
    __syncthreads();
#pragma unroll
    for (int i = 0; i < 4; ++i) {       // W tile: 1024 float4
      int q = tid + 256 * i;
      int k = q >> 5, j = (q & 31) * 4;
      float4 wv = *(const float4*)&W[(kt + k) * 128 + j];
      *(float4*)&Ws[k][j] = wv;
    }
#pragma unroll
    for (int i = 0; i < 4; ++i) {       // X tile (transposed into LDS)
      int q = tid + 256 * i;
      int r = q >> 3, kk = (q & 7) * 4;
      float4 xv = make_float4(0.f, 0.f, 0.f, 0.f);
      if (n0 + r < nnodes) xv = *(const float4*)&X[(size_t)(n0 + r) * 128 + kt + kk];
      XsT[kk + 0][r] = xv.x; XsT[kk + 1][r] = xv.y;
      XsT[kk + 2][r] = xv.z; XsT[kk + 3][r] = xv.w;
    }
    __syncthreads();
#pragma unroll
    for (int k = 0; k < 32; ++k) {
      float4 xa = *(const float4*)&XsT[k][r0];
      float4 xb = *(const float4*)&XsT[k][r0 + 4];
      float4 wa = *(const float4*)&Ws[k][j0];
      float4 wb = *(const float4*)&Ws[k][j0 + 4];
      float xs[8] = {xa.x, xa.y, xa.z, xa.w, xb.x, xb.y, xb.z, xb.w};
      float wv[8] = {wa.x, wa.y, wa.z, wa.w, wb.x, wb.y, wb.z, wb.w};
#pragma unroll
      for (int i = 0; i < 8; i++)
#pragma unroll
        for (int j = 0; j < 8; j++) acc[i][j] += xs[i] * wv[j];
    }
  }
  float as_[8], ad_[8];
#pragma unroll
  for (int j = 0; j < 8; j++) { as_[j] = avs[j0 + j]; ad_[j] = avd[j0 + j]; }
  const int head = (j0 >= 64) ? 1 : 0;
#pragma unroll
  for (int i = 0; i < 8; i++) {
    int n = n0 + r0 + i;
    float ps = 0.f, pd = 0.f;
#pragma unroll
    for (int j = 0; j < 8; j++) { ps += acc[i][j] * as_[j]; pd += acc[i][j] * ad_[j]; }
    atomicAdd(&es_s[head][r0 + i], ps);
    atomicAdd(&ed_s[head][r0 + i], pd);
    if (n < nnodes) {
      float4 v0 = make_float4(acc[i][0], acc[i][1], acc[i][2], acc[i][3]);
      float4 v1 = make_float4(acc[i][4], acc[i][5], acc[i][6], acc[i][7]);
      *(float4*)&hfeat[(size_t)n * 128 + j0] = v0;
      *(float4*)&hfeat[(size_t)n * 128 + j0 + 4] = v1;
    }
  }
  __syncthreads();
  if (tid < 128) {
    int n = n0 + tid;
    if (n < nnodes) {
      es[n * 2 + 0] = es_s[0][tid]; es[n * 2 + 1] = es_s[1][tid];
      ed[n * 2 + 0] = ed_s[0][tid]; ed[n * 2 + 1] = ed_s[1][tid];
    }
  }
}

// ---------------- per-edge softmax weights (both heads) ----------------
__global__ __launch_bounds__(256) void edge_w_kernel(
    const float* __restrict__ es, const float* __restrict__ ed,
    const int* __restrict__ csr_src, const int* __restrict__ csr_dst,
    float2* __restrict__ wbuf)
{
  int i = blockIdx.x * 256 + threadIdx.x;
  if (i >= ET) return;
  int s = csr_src[i], d = csr_dst[i];
  float2 esv = ((const float2*)es)[s];
  float2 edv = ((const float2*)ed)[d];
  float e0 = esv.x + edv.x, e1 = esv.y + edv.y;
  e0 = (e0 > 0.f) ? e0 : 0.2f * e0;
  e1 = (e1 > 0.f) ? e1 : 0.2f * e1;
  wbuf[i] = make_float2(__expf(e0), __expf(e1));
}

// ---------------- aggregation: one wave per node, both heads ----------------
__global__ __launch_bounds__(256) void aggregate_kernel(
    const float* __restrict__ hfeat, const float2* __restrict__ wbuf,
    const int* __restrict__ rowptr, const int* __restrict__ csr_src,
    const float* __restrict__ bias, float* __restrict__ out, int nnodes)
{
  int n = (blockIdx.x * blockDim.x + threadIdx.x) >> 6;
  int lane = threadIdx.x & 63;
  if (n >= nnodes) return;
  int beg = rowptr[n], end = rowptr[n + 1];
  float acc0 = 0.f, acc1 = 0.f, den0 = 0.f, den1 = 0.f;
  int i = beg;
  for (; i + 2 <= end; i += 2) {
    int s0 = csr_src[i], s1 = csr_src[i + 1];
    float2 w0 = wbuf[i], w1 = wbuf[i + 1];
    const float* p0 = &hfeat[(size_t)s0 * 128 + lane];
    const float* p1 = &hfeat[(size_t)s1 * 128 + lane];
    float h00 = p0[0], h01 = p0[64];
    float h10 = p1[0], h11 = p1[64];
    acc0 += w0.x * h00 + w1.x * h10;
    acc1 += w0.y * h01 + w1.y * h11;
    den0 += w0.x + w1.x;
    den1 += w0.y + w1.y;
  }
  if (i < end) {
    int s0 = csr_src[i];
    float2 w0 = wbuf[i];
    const float* p0 = &hfeat[(size_t)s0 * 128 + lane];
    acc0 += w0.x * p0[0];
    acc1 += w0.y * p0[64];
    den0 += w0.x;
    den1 += w0.y;
  }
  float v0 = acc0 / den0 + bias[lane];
  float v1 = acc1 / den1 + bias[64 + lane];
  v0 = (v0 > 0.f) ? v0 : (__expf(v0) - 1.f);
  v1 = (v1 > 0.f) ? v1 : (__expf(v1) - 1.f);
  out[(size_t)n * 128 + lane] = v0;
  out[(size_t)n * 128 + 64 + lane] = v1;
}

// ---------------- final linear (256->40) + log_softmax, tiled GEMM ----------------
__global__ __launch_bounds__(256) void final_kernel(
    const float* __restrict__ h1, const float* __restrict__ h2,
    const float* __restrict__ lw, const float* __restrict__ lb,
    float* __restrict__ out, int nnodes)
{
  __shared__ __align__(16) float Hs[64][33];
  __shared__ __align__(16) float Ws2[32 * 40];
  const int tid = threadIdx.x;
  const int m = tid >> 2, q = tid & 3;
  const int n0 = blockIdx.x * 64;

  float bj[10];
#pragma unroll
  for (int j = 0; j < 10; ++j) bj[j] = lb[q * 10 + j];

  float acc[10];
#pragma unroll
  for (int j = 0; j < 10; ++j) acc[j] = 0.f;

  for (int kc = 0; kc < 256; kc += 32) {
    __syncthreads();
#pragma unroll
    for (int it = 0; it < 2; ++it) {
      int idx = tid + it * 256;
      int nd = idx >> 3, kk = (idx & 7) * 4;
      int n = n0 + nd;
      float4 v = make_float4(0.f, 0.f, 0.f, 0.f);
      if (n < nnodes) {
        const float* src = (kc < 128) ? &h1[(size_t)n * 128 + kc + kk]
                                      : &h2[(size_t)n * 128 + (kc - 128) + kk];
        v = *(const float4*)src;
      }
      Hs[nd][kk + 0] = v.x; Hs[nd][kk + 1] = v.y;
      Hs[nd][kk + 2] = v.z; Hs[nd][kk + 3] = v.w;
    }
    {
      float4 v = *(const float4*)&lw[kc * 40 + tid * 4];
      *(float4*)&Ws2[tid * 4] = v;
      if (tid < 64) {
        float4 v2 = *(const float4*)&lw[kc * 40 + (256 + tid) * 4];
        *(float4*)&Ws2[(256 + tid) * 4] = v2;
      }
    }
    __syncthreads();
#pragma unroll
    for (int k = 0; k < 32; ++k) {
      float a = Hs[m][k];
      const float* wr = &Ws2[k * 40 + q * 10];
#pragma unroll
      for (int j = 0; j < 10; ++j) acc[j] = fmaf(a, wr[j], acc[j]);
    }
  }

  float mx = -INFINITY;
#pragma unroll
  for (int j = 0; j < 10; ++j) { acc[j] += bj[j]; mx = fmaxf(mx, acc[j]); }
  mx = fmaxf(mx, __shfl_xor(mx, 1));
  mx = fmaxf(mx, __shfl_xor(mx, 2));
  float s = 0.f;
#pragma unroll
  for (int j = 0; j < 10; ++j) s += __expf(acc[j] - mx);
  s += __shfl_xor(s, 1);
  s += __shfl_xor(s, 2);
  float lg = mx + __logf(s);
  int n = n0 + m;
  if (n < nnodes) {
#pragma unroll
    for (int j = 0; j < 10; ++j) out[(size_t)n * 40 + q * 10 + j] = acc[j] - lg;
  }
}

// ---------------- launch ----------------

extern "C" void kernel_launch(void* const* d_in, const int* in_sizes, int n_in,
                              void* d_out, int out_size, void* d_ws, size_t ws_size,
                              hipStream_t stream) {
  const float* x   = (const float*)d_in[0];
  const int*   ei  = (const int*)d_in[1];
  const float* W0  = (const float*)d_in[2];
  const float* as0 = (const float*)d_in[3];
  const float* ad0 = (const float*)d_in[4];
  const float* b0  = (const float*)d_in[5];
  const float* W1  = (const float*)d_in[6];
  const float* as1 = (const float*)d_in[7];
  const float* ad1 = (const float*)d_in[8];
  const float* b1  = (const float*)d_in[9];
  const float* lw  = (const float*)d_in[10];
  const float* lb  = (const float*)d_in[11];
  float* out = (float*)d_out;

  char* p = (char*)d_ws;
  auto carve = [&](size_t bytes) { char* r = p; p += (bytes + 255) & ~(size_t)255; return r; };
  float* hfeat = (float*)carve((size_t)NN * 128 * 4);
  float* h1o   = (float*)carve((size_t)NN * 128 * 4);
  float* h2o   = (float*)carve((size_t)NN * 128 * 4);
  float* es    = (float*)carve((size_t)NN * 2 * 4);
  float* ed    = (float*)carve((size_t)NN * 2 * 4);
  int* rowptr  = (int*)carve((size_t)(NN + 1) * 4);
  int* cnt     = (int*)carve((size_t)NN * 4);
  int* csr     = (int*)carve((size_t)ET * 4);
  int* csrd    = (int*)carve((size_t)ET * 4);
  float2* wbuf = (float2*)carve((size_t)ET * 8);
  int* bsum    = (int*)carve((size_t)NB * 4);
  int* boff    = (int*)carve((size_t)NB * 4);

  // CSR build (reused by both layers)
  zero_int_kernel<<<(NN + 1023) / 1024, 1024, 0, stream>>>(cnt, NN);
  count_kernel<<<(ET + 255) / 256, 256, 0, stream>>>(ei, cnt);
  scan_l1_kernel<<<NB, 256, 0, stream>>>(cnt, rowptr, bsum);
  scan_l2_kernel<<<1, 256, 0, stream>>>(bsum, boff, rowptr);
  scan_add_kernel<<<NB, 256, 0, stream>>>(rowptr, boff);
  zero_int_kernel<<<(NN + 1023) / 1024, 1024, 0, stream>>>(cnt, NN);
  scatter_kernel<<<(ET + 255) / 256, 256, 0, stream>>>(ei, rowptr, cnt, csr, csrd);

  // layer 1
  gemm_att_kernel<<<(NN + 127) / 128, 256, 0, stream>>>(x, W0, as0, ad0, hfeat, es, ed, NN);
  edge_w_kernel<<<(ET + 255) / 256, 256, 0, stream>>>(es, ed, csr, csrd, wbuf);
  aggregate_kernel<<<(NN * 64 + 255) / 256, 256, 0, stream>>>(hfeat, wbuf, rowptr, csr, b0, h1o, NN);
  // layer 2
  gemm_att_kernel<<<(NN + 127) / 128, 256, 0, stream>>>(h1o, W1, as1, ad1, hfeat, es, ed, NN);
  edge_w_kernel<<<(ET + 255) / 256, 256, 0, stream>>>(es, ed, csr, csrd, wbuf);
  aggregate_kernel<<<(NN * 64 + 255) / 256, 256, 0, stream>>>(hfeat, wbuf, rowptr, csr, b1, h2o, NN);
  // head
  final_kernel<<<(NN + 63) / 64, 256, 0, stream>>>(h1o, h2o, lw, lb, out, NN);
}

// Round 4
// 470.566 us; speedup vs baseline: 1.7095x; 1.0165x over previous
//
#include <hip/hip_runtime.h>
#include <math.h>

#define NN 50000
#define E0 800000
#define ET 850000
#define NB 196  // ceil(NN/256) scan blocks

// ---------------- CSR build ----------------

__global__ void zero_int_kernel(int* __restrict__ p, int n) {
  int i = blockIdx.x * blockDim.x + threadIdx.x;
  if (i < n) p[i] = 0;
}

__global__ void count_kernel(const int* __restrict__ ei, int* __restrict__ cnt) {
  int e = blockIdx.x * blockDim.x + threadIdx.x;
  if (e >= ET) return;
  int dst = (e < E0) ? ei[E0 + e] : (e - E0);
  atomicAdd(&cnt[dst], 1);
}

// two-level scan: L1 per-256 block scan, L2 scan of block sums, L3 add offsets
__global__ __launch_bounds__(256) void scan_l1_kernel(const int* __restrict__ cnt,
                                                      int* __restrict__ rowptr,
                                                      int* __restrict__ bsum) {
  __shared__ int s[256];
  int i = blockIdx.x * 256 + threadIdx.x;
  int v = (i < NN) ? cnt[i] : 0;
  int val = v;
  s[threadIdx.x] = val;
  __syncthreads();
#pragma unroll
  for (int off = 1; off < 256; off <<= 1) {
    int t = (threadIdx.x >= (unsigned)off) ? s[threadIdx.x - off] : 0;
    __syncthreads();
    val += t;
    s[threadIdx.x] = val;
    __syncthreads();
  }
  if (i < NN) rowptr[i] = val - v;  // block-local exclusive
  if (threadIdx.x == 255) bsum[blockIdx.x] = val;
}

__global__ __launch_bounds__(256) void scan_l2_kernel(const int* __restrict__ bsum,
                                                      int* __restrict__ boff,
                                                      int* __restrict__ rowptr) {
  __shared__ int s[256];
  int i = threadIdx.x;
  int v = (i < NB) ? bsum[i] : 0;
  int val = v;
  s[i] = val;
  __syncthreads();
#pragma unroll
  for (int off = 1; off < 256; off <<= 1) {
    int t = (i >= (unsigned)off) ? s[i - off] : 0;
    __syncthreads();
    val += t;
    s[i] = val;
    __syncthreads();
  }
  if (i < NB) boff[i] = val - v;  // exclusive
  if (i == NB - 1) rowptr[NN] = val;  // total = ET
}

__global__ __launch_bounds__(256) void scan_add_kernel(int* __restrict__ rowptr,
                                                       const int* __restrict__ boff) {
  int i = blockIdx.x * 256 + threadIdx.x;
  if (i < NN) rowptr[i] += boff[blockIdx.x];
}

__global__ void scatter_kernel(const int* __restrict__ ei, const int* __restrict__ rowptr,
                               int* __restrict__ cursor, int* __restrict__ csr_src,
                               int* __restrict__ csr_dst) {
  int e = blockIdx.x * blockDim.x + threadIdx.x;
  if (e >= ET) return;
  int src, dst;
  if (e < E0) { src = ei[e]; dst = ei[E0 + e]; }
  else        { src = e - E0; dst = src; }
  int pos = rowptr[dst] + atomicAdd(&cursor[dst], 1);
  csr_src[pos] = src;
  csr_dst[pos] = dst;
}

// ---------------- GEMM (X @ W) + per-node attention logits ----------------
// 64-node x 128-col tile per 256-thread block. Thread (rr=tid&15, cc=tid>>4)
// owns rows 4rr..4rr+3, cols {4cc..4cc+3} (head0) and {64+4cc..+3} (head1).
__global__ __launch_bounds__(256, 4) void gemm_att_kernel(
    const float* __restrict__ X, const float* __restrict__ W,
    const float* __restrict__ avs, const float* __restrict__ avd,
    float* __restrict__ hfeat, float* __restrict__ es, float* __restrict__ ed,
    int nnodes)
{
  __shared__ float Ws[32][128];    // 16 KB k-tile of W
  __shared__ float XsT[32][72];    // 9 KB transposed X tile (72: pad, 16B-aligned rows)
  __shared__ float es_s[2][64];
  __shared__ float ed_s[2][64];
  const int tid = threadIdx.x;
  const int n0 = blockIdx.x * 64;
  const int rr = tid & 15, cc = tid >> 4;
  const int r0 = rr * 4, c0 = cc * 4;
  if (tid < 128) { es_s[tid >> 6][tid & 63] = 0.f; ed_s[tid >> 6][tid & 63] = 0.f; }
  float acc[4][8];
#pragma unroll
  for (int i = 0; i < 4; i++)
#pragma unroll
    for (int j = 0; j < 8; j++) acc[i][j] = 0.f;

  float* wflat = &Ws[0][0];
  for (int kt = 0; kt < 128; kt += 32) {
    __syncthreads();
#pragma unroll
    for (int i = 0; i < 4; ++i) {       // W chunk: rows kt..kt+31, contiguous 16 KB
      int q = tid + 256 * i;
      *(float4*)&wflat[q * 4] = *(const float4*)&W[kt * 128 + q * 4];
    }
#pragma unroll
    for (int i = 0; i < 2; ++i) {       // X tile: 64 nodes x 32 k, transposed into LDS
      int q = tid + 256 * i;
      int nd = q >> 3, kk = (q & 7) * 4;
      float4 xv = make_float4(0.f, 0.f, 0.f, 0.f);
      if (n0 + nd < nnodes) xv = *(const float4*)&X[(size_t)(n0 + nd) * 128 + kt + kk];
      XsT[kk + 0][nd] = xv.x; XsT[kk + 1][nd] = xv.y;
      XsT[kk + 2][nd] = xv.z; XsT[kk + 3][nd] = xv.w;
    }
    __syncthreads();
#pragma unroll
    for (int k = 0; k < 32; ++k) {
      float4 xa = *(const float4*)&XsT[k][r0];
      float4 wa = *(const float4*)&Ws[k][c0];
      float4 wb = *(const float4*)&Ws[k][64 + c0];
      float xs[4] = {xa.x, xa.y, xa.z, xa.w};
      float wv[8] = {wa.x, wa.y, wa.z, wa.w, wb.x, wb.y, wb.z, wb.w};
#pragma unroll
      for (int i = 0; i < 4; i++)
#pragma unroll
        for (int j = 0; j < 8; j++) acc[i][j] += xs[i] * wv[j];
    }
  }
  // attention partials (per head) + hfeat store
  float as0_[4], as1_[4], ad0_[4], ad1_[4];
#pragma unroll
  for (int j = 0; j < 4; j++) {
    as0_[j] = avs[c0 + j];      ad0_[j] = avd[c0 + j];
    as1_[j] = avs[64 + c0 + j]; ad1_[j] = avd[64 + c0 + j];
  }
#pragma unroll
  for (int i = 0; i < 4; i++) {
    int r = r0 + i;
    int n = n0 + r;
    float ps0 = 0.f, pd0 = 0.f, ps1 = 0.f, pd1 = 0.f;
#pragma unroll
    for (int j = 0; j < 4; j++) {
      ps0 += acc[i][j] * as0_[j];     pd0 += acc[i][j] * ad0_[j];
      ps1 += acc[i][4 + j] * as1_[j]; pd1 += acc[i][4 + j] * ad1_[j];
    }
    atomicAdd(&es_s[0][r], ps0); atomicAdd(&es_s[1][r], ps1);
    atomicAdd(&ed_s[0][r], pd0); atomicAdd(&ed_s[1][r], pd1);
    if (n < nnodes) {
      *(float4*)&hfeat[(size_t)n * 128 + c0]      = make_float4(acc[i][0], acc[i][1], acc[i][2], acc[i][3]);
      *(float4*)&hfeat[(size_t)n * 128 + 64 + c0] = make_float4(acc[i][4], acc[i][5], acc[i][6], acc[i][7]);
    }
  }
  __syncthreads();
  if (tid < 64) {
    int n = n0 + tid;
    if (n < nnodes) {
      es[n * 2 + 0] = es_s[0][tid]; es[n * 2 + 1] = es_s[1][tid];
      ed[n * 2 + 0] = ed_s[0][tid]; ed[n * 2 + 1] = ed_s[1][tid];
    }
  }
}

// ---------------- per-edge softmax weights (both heads) ----------------
__global__ __launch_bounds__(256) void edge_w_kernel(
    const float* __restrict__ es, const float* __restrict__ ed,
    const int* __restrict__ csr_src, const int* __restrict__ csr_dst,
    float2* __restrict__ wbuf)
{
  int i = blockIdx.x * 256 + threadIdx.x;
  if (i >= ET) return;
  int s = csr_src[i], d = csr_dst[i];
  float2 esv = ((const float2*)es)[s];
  float2 edv = ((const float2*)ed)[d];
  float e0 = esv.x + edv.x, e1 = esv.y + edv.y;
  e0 = (e0 > 0.f) ? e0 : 0.2f * e0;
  e1 = (e1 > 0.f) ? e1 : 0.2f * e1;
  wbuf[i] = make_float2(__expf(e0), __expf(e1));
}

// ---------------- aggregation: one wave per node, both heads ----------------
__global__ __launch_bounds__(256) void aggregate_kernel(
    const float* __restrict__ hfeat, const float2* __restrict__ wbuf,
    const int* __restrict__ rowptr, const int* __restrict__ csr_src,
    const float* __restrict__ bias, float* __restrict__ out, int nnodes)
{
  int n = (blockIdx.x * blockDim.x + threadIdx.x) >> 6;
  int lane = threadIdx.x & 63;
  if (n >= nnodes) return;
  int beg = rowptr[n], end = rowptr[n + 1];
  float acc0 = 0.f, acc1 = 0.f, den0 = 0.f, den1 = 0.f;
  int i = beg;
  for (; i + 2 <= end; i += 2) {
    int s0 = csr_src[i], s1 = csr_src[i + 1];
    float2 w0 = wbuf[i], w1 = wbuf[i + 1];
    const float* p0 = &hfeat[(size_t)s0 * 128 + lane];
    const float* p1 = &hfeat[(size_t)s1 * 128 + lane];
    float h00 = p0[0], h01 = p0[64];
    float h10 = p1[0], h11 = p1[64];
    acc0 += w0.x * h00 + w1.x * h10;
    acc1 += w0.y * h01 + w1.y * h11;
    den0 += w0.x + w1.x;
    den1 += w0.y + w1.y;
  }
  if (i < end) {
    int s0 = csr_src[i];
    float2 w0 = wbuf[i];
    const float* p0 = &hfeat[(size_t)s0 * 128 + lane];
    acc0 += w0.x * p0[0];
    acc1 += w0.y * p0[64];
    den0 += w0.x;
    den1 += w0.y;
  }
  float v0 = acc0 / den0 + bias[lane];
  float v1 = acc1 / den1 + bias[64 + lane];
  v0 = (v0 > 0.f) ? v0 : (__expf(v0) - 1.f);
  v1 = (v1 > 0.f) ? v1 : (__expf(v1) - 1.f);
  out[(size_t)n * 128 + lane] = v0;
  out[(size_t)n * 128 + 64 + lane] = v1;
}

// ---------------- final linear (256->40) + log_softmax, tiled GEMM ----------------
__global__ __launch_bounds__(256) void final_kernel(
    const float* __restrict__ h1, const float* __restrict__ h2,
    const float* __restrict__ lw, const float* __restrict__ lb,
    float* __restrict__ out, int nnodes)
{
  __shared__ __align__(16) float Hs[64][33];
  __shared__ __align__(16) float Ws2[32 * 40];
  const int tid = threadIdx.x;
  const int m = tid >> 2, q = tid & 3;
  const int n0 = blockIdx.x * 64;

  float bj[10];
#pragma unroll
  for (int j = 0; j < 10; ++j) bj[j] = lb[q * 10 + j];

  float acc[10];
#pragma unroll
  for (int j = 0; j < 10; ++j) acc[j] = 0.f;

  for (int kc = 0; kc < 256; kc += 32) {
    __syncthreads();
#pragma unroll
    for (int it = 0; it < 2; ++it) {
      int idx = tid + it * 256;
      int nd = idx >> 3, kk = (idx & 7) * 4;
      int n = n0 + nd;
      float4 v = make_float4(0.f, 0.f, 0.f, 0.f);
      if (n < nnodes) {
        const float* src = (kc < 128) ? &h1[(size_t)n * 128 + kc + kk]
                                      : &h2[(size_t)n * 128 + (kc - 128) + kk];
        v = *(const float4*)src;
      }
      Hs[nd][kk + 0] = v.x; Hs[nd][kk + 1] = v.y;
      Hs[nd][kk + 2] = v.z; Hs[nd][kk + 3] = v.w;
    }
    {
      float4 v = *(const float4*)&lw[kc * 40 + tid * 4];
      *(float4*)&Ws2[tid * 4] = v;
      if (tid < 64) {
        float4 v2 = *(const float4*)&lw[kc * 40 + (256 + tid) * 4];
        *(float4*)&Ws2[(256 + tid) * 4] = v2;
      }
    }
    __syncthreads();
#pragma unroll
    for (int k = 0; k < 32; ++k) {
      float a = Hs[m][k];
      const float* wr = &Ws2[k * 40 + q * 10];
#pragma unroll
      for (int j = 0; j < 10; ++j) acc[j] = fmaf(a, wr[j], acc[j]);
    }
  }

  float mx = -INFINITY;
#pragma unroll
  for (int j = 0; j < 10; ++j) { acc[j] += bj[j]; mx = fmaxf(mx, acc[j]); }
  mx = fmaxf(mx, __shfl_xor(mx, 1));
  mx = fmaxf(mx, __shfl_xor(mx, 2));
  float s = 0.f;
#pragma unroll
  for (int j = 0; j < 10; ++j) s += __expf(acc[j] - mx);
  s += __shfl_xor(s, 1);
  s += __shfl_xor(s, 2);
  float lg = mx + __logf(s);
  int n = n0 + m;
  if (n < nnodes) {
#pragma unroll
    for (int j = 0; j < 10; ++j) out[(size_t)n * 40 + q * 10 + j] = acc[j] - lg;
  }
}

// ---------------- launch ----------------

extern "C" void kernel_launch(void* const* d_in, const int* in_sizes, int n_in,
                              void* d_out, int out_size, void* d_ws, size_t ws_size,
                              hipStream_t stream) {
  const float* x   = (const float*)d_in[0];
  const int*   ei  = (const int*)d_in[1];
  const float* W0  = (const float*)d_in[2];
  const float* as0 = (const float*)d_in[3];
  const float* ad0 = (const float*)d_in[4];
  const float* b0  = (const float*)d_in[5];
  const float* W1  = (const float*)d_in[6];
  const float* as1 = (const float*)d_in[7];
  const float* ad1 = (const float*)d_in[8];
  const float* b1  = (const float*)d_in[9];
  const float* lw  = (const float*)d_in[10];
  const float* lb  = (const float*)d_in[11];
  float* out = (float*)d_out;

  char* p = (char*)d_ws;
  auto carve = [&](size_t bytes) { char* r = p; p += (bytes + 255) & ~(size_t)255; return r; };
  float* hfeat = (float*)carve((size_t)NN * 128 * 4);
  float* h1o   = (float*)carve((size_t)NN * 128 * 4);
  float* h2o   = (float*)carve((size_t)NN * 128 * 4);
  float* es    = (float*)carve((size_t)NN * 2 * 4);
  float* ed    = (float*)carve((size_t)NN * 2 * 4);
  int* rowptr  = (int*)carve((size_t)(NN + 1) * 4);
  int* cnt     = (int*)carve((size_t)NN * 4);
  int* csr     = (int*)carve((size_t)ET * 4);
  int* csrd    = (int*)carve((size_t)ET * 4);
  float2* wbuf = (float2*)carve((size_t)ET * 8);
  int* bsum    = (int*)carve((size_t)NB * 4);
  int* boff    = (int*)carve((size_t)NB * 4);

  // CSR build (reused by both layers)
  zero_int_kernel<<<(NN + 1023) / 1024, 1024, 0, stream>>>(cnt, NN);
  count_kernel<<<(ET + 255) / 256, 256, 0, stream>>>(ei, cnt);
  scan_l1_kernel<<<NB, 256, 0, stream>>>(cnt, rowptr, bsum);
  scan_l2_kernel<<<1, 256, 0, stream>>>(bsum, boff, rowptr);
  scan_add_kernel<<<NB, 256, 0, stream>>>(rowptr, boff);
  zero_int_kernel<<<(NN + 1023) / 1024, 1024, 0, stream>>>(cnt, NN);
  scatter_kernel<<<(ET + 255) / 256, 256, 0, stream>>>(ei, rowptr, cnt, csr, csrd);

  // layer 1
  gemm_att_kernel<<<(NN + 63) / 64, 256, 0, stream>>>(x, W0, as0, ad0, hfeat, es, ed, NN);
  edge_w_kernel<<<(ET + 255) / 256, 256, 0, stream>>>(es, ed, csr, csrd, wbuf);
  aggregate_kernel<<<(NN * 64 + 255) / 256, 256, 0, stream>>>(hfeat, wbuf, rowptr, csr, b0, h1o, NN);
  // layer 2
  gemm_att_kernel<<<(NN + 63) / 64, 256, 0, stream>>>(h1o, W1, as1, ad1, hfeat, es, ed, NN);
  edge_w_kernel<<<(ET + 255) / 256, 256, 0, stream>>>(es, ed, csr, csrd, wbuf);
  aggregate_kernel<<<(NN * 64 + 255) / 256, 256, 0, stream>>>(hfeat, wbuf, rowptr, csr, b1, h2o, NN);
  // head
  final_kernel<<<(NN + 63) / 64, 256, 0, stream>>>(h1o, h2o, lw, lb, out, NN);
}

// Round 5
// 452.564 us; speedup vs baseline: 1.7775x; 1.0398x over previous
//
#include <hip/hip_runtime.h>
#include <math.h>

#define NN 50000
#define E0 800000
#define ET 850000
#define NB 196  // ceil(NN/256) scan blocks

typedef unsigned int uint32;
typedef unsigned short ushort16;

__device__ __forceinline__ ushort16 f2bf(float f) {
  uint32 u = __float_as_uint(f);
  return (ushort16)((u + 0x7FFFu + ((u >> 16) & 1u)) >> 16);  // RNE
}

// ---------------- CSR build ----------------

__global__ void zero_int_kernel(int* __restrict__ p, int n) {
  int i = blockIdx.x * blockDim.x + threadIdx.x;
  if (i < n) p[i] = 0;
}

__global__ void count_kernel(const int* __restrict__ ei, int* __restrict__ cnt) {
  int e = blockIdx.x * blockDim.x + threadIdx.x;
  if (e >= ET) return;
  int dst = (e < E0) ? ei[E0 + e] : (e - E0);
  atomicAdd(&cnt[dst], 1);
}

// two-level scan: L1 per-256 block scan, L2 scan of block sums, L3 add offsets
__global__ __launch_bounds__(256) void scan_l1_kernel(const int* __restrict__ cnt,
                                                      int* __restrict__ rowptr,
                                                      int* __restrict__ bsum) {
  __shared__ int s[256];
  int i = blockIdx.x * 256 + threadIdx.x;
  int v = (i < NN) ? cnt[i] : 0;
  int val = v;
  s[threadIdx.x] = val;
  __syncthreads();
#pragma unroll
  for (int off = 1; off < 256; off <<= 1) {
    int t = (threadIdx.x >= (unsigned)off) ? s[threadIdx.x - off] : 0;
    __syncthreads();
    val += t;
    s[threadIdx.x] = val;
    __syncthreads();
  }
  if (i < NN) rowptr[i] = val - v;  // block-local exclusive
  if (threadIdx.x == 255) bsum[blockIdx.x] = val;
}

__global__ __launch_bounds__(256) void scan_l2_kernel(const int* __restrict__ bsum,
                                                      int* __restrict__ boff,
                                                      int* __restrict__ rowptr) {
  __shared__ int s[256];
  int i = threadIdx.x;
  int v = (i < NB) ? bsum[i] : 0;
  int val = v;
  s[i] = val;
  __syncthreads();
#pragma unroll
  for (int off = 1; off < 256; off <<= 1) {
    int t = (i >= (unsigned)off) ? s[i - off] : 0;
    __syncthreads();
    val += t;
    s[i] = val;
    __syncthreads();
  }
  if (i < NB) boff[i] = val - v;  // exclusive
  if (i == NB - 1) rowptr[NN] = val;  // total = ET
}

__global__ __launch_bounds__(256) void scan_add_kernel(int* __restrict__ rowptr,
                                                       const int* __restrict__ boff) {
  int i = blockIdx.x * 256 + threadIdx.x;
  if (i < NN) rowptr[i] += boff[blockIdx.x];
}

__global__ void scatter_kernel(const int* __restrict__ ei, const int* __restrict__ rowptr,
                               int* __restrict__ cursor, int* __restrict__ csr_src,
                               int* __restrict__ csr_dst) {
  int e = blockIdx.x * blockDim.x + threadIdx.x;
  if (e >= ET) return;
  int src, dst;
  if (e < E0) { src = ei[e]; dst = ei[E0 + e]; }
  else        { src = e - E0; dst = src; }
  int pos = rowptr[dst] + atomicAdd(&cursor[dst], 1);
  csr_src[pos] = src;
  csr_dst[pos] = dst;
}

// ---------------- GEMM (X @ W) + per-node attention logits ----------------
// hfeat is written in bf16 (consumed only by aggregate_kernel's gather).
__global__ __launch_bounds__(256, 4) void gemm_att_kernel(
    const float* __restrict__ X, const float* __restrict__ W,
    const float* __restrict__ avs, const float* __restrict__ avd,
    ushort16* __restrict__ hfeat, float* __restrict__ es, float* __restrict__ ed,
    int nnodes)
{
  __shared__ float Ws[32][128];    // 16 KB k-tile of W
  __shared__ float XsT[32][72];    // 9 KB transposed X tile
  __shared__ float es_s[2][64];
  __shared__ float ed_s[2][64];
  const int tid = threadIdx.x;
  const int n0 = blockIdx.x * 64;
  const int rr = tid & 15, cc = tid >> 4;
  const int r0 = rr * 4, c0 = cc * 4;
  if (tid < 128) { es_s[tid >> 6][tid & 63] = 0.f; ed_s[tid >> 6][tid & 63] = 0.f; }
  float acc[4][8];
#pragma unroll
  for (int i = 0; i < 4; i++)
#pragma unroll
    for (int j = 0; j < 8; j++) acc[i][j] = 0.f;

  float* wflat = &Ws[0][0];
  for (int kt = 0; kt < 128; kt += 32) {
    __syncthreads();
#pragma unroll
    for (int i = 0; i < 4; ++i) {       // W chunk: rows kt..kt+31
      int q = tid + 256 * i;
      *(float4*)&wflat[q * 4] = *(const float4*)&W[kt * 128 + q * 4];
    }
#pragma unroll
    for (int i = 0; i < 2; ++i) {       // X tile: 64 nodes x 32 k, transposed
      int q = tid + 256 * i;
      int nd = q >> 3, kk = (q & 7) * 4;
      float4 xv = make_float4(0.f, 0.f, 0.f, 0.f);
      if (n0 + nd < nnodes) xv = *(const float4*)&X[(size_t)(n0 + nd) * 128 + kt + kk];
      XsT[kk + 0][nd] = xv.x; XsT[kk + 1][nd] = xv.y;
      XsT[kk + 2][nd] = xv.z; XsT[kk + 3][nd] = xv.w;
    }
    __syncthreads();
#pragma unroll
    for (int k = 0; k < 32; ++k) {
      float4 xa = *(const float4*)&XsT[k][r0];
      float4 wa = *(const float4*)&Ws[k][c0];
      float4 wb = *(const float4*)&Ws[k][64 + c0];
      float xs[4] = {xa.x, xa.y, xa.z, xa.w};
      float wv[8] = {wa.x, wa.y, wa.z, wa.w, wb.x, wb.y, wb.z, wb.w};
#pragma unroll
      for (int i = 0; i < 4; i++)
#pragma unroll
        for (int j = 0; j < 8; j++) acc[i][j] += xs[i] * wv[j];
    }
  }
  // attention partials (per head) + bf16 hfeat store
  float as0_[4], as1_[4], ad0_[4], ad1_[4];
#pragma unroll
  for (int j = 0; j < 4; j++) {
    as0_[j] = avs[c0 + j];      ad0_[j] = avd[c0 + j];
    as1_[j] = avs[64 + c0 + j]; ad1_[j] = avd[64 + c0 + j];
  }
#pragma unroll
  for (int i = 0; i < 4; i++) {
    int r = r0 + i;
    int n = n0 + r;
    float ps0 = 0.f, pd0 = 0.f, ps1 = 0.f, pd1 = 0.f;
#pragma unroll
    for (int j = 0; j < 4; j++) {
      ps0 += acc[i][j] * as0_[j];     pd0 += acc[i][j] * ad0_[j];
      ps1 += acc[i][4 + j] * as1_[j]; pd1 += acc[i][4 + j] * ad1_[j];
    }
    atomicAdd(&es_s[0][r], ps0); atomicAdd(&es_s[1][r], ps1);
    atomicAdd(&ed_s[0][r], pd0); atomicAdd(&ed_s[1][r], pd1);
    if (n < nnodes) {
      ushort4 u0, u1;
      u0.x = f2bf(acc[i][0]); u0.y = f2bf(acc[i][1]); u0.z = f2bf(acc[i][2]); u0.w = f2bf(acc[i][3]);
      u1.x = f2bf(acc[i][4]); u1.y = f2bf(acc[i][5]); u1.z = f2bf(acc[i][6]); u1.w = f2bf(acc[i][7]);
      *(ushort4*)&hfeat[(size_t)n * 128 + c0]      = u0;
      *(ushort4*)&hfeat[(size_t)n * 128 + 64 + c0] = u1;
    }
  }
  __syncthreads();
  if (tid < 64) {
    int n = n0 + tid;
    if (n < nnodes) {
      es[n * 2 + 0] = es_s[0][tid]; es[n * 2 + 1] = es_s[1][tid];
      ed[n * 2 + 0] = ed_s[0][tid]; ed[n * 2 + 1] = ed_s[1][tid];
    }
  }
}

// ---------------- per-edge softmax weights (both heads) ----------------
__global__ __launch_bounds__(256) void edge_w_kernel(
    const float* __restrict__ es, const float* __restrict__ ed,
    const int* __restrict__ csr_src, const int* __restrict__ csr_dst,
    float2* __restrict__ wbuf)
{
  int i = blockIdx.x * 256 + threadIdx.x;
  if (i >= ET) return;
  int s = csr_src[i], d = csr_dst[i];
  float2 esv = ((const float2*)es)[s];
  float2 edv = ((const float2*)ed)[d];
  float e0 = esv.x + edv.x, e1 = esv.y + edv.y;
  e0 = (e0 > 0.f) ? e0 : 0.2f * e0;
  e1 = (e1 > 0.f) ? e1 : 0.2f * e1;
  wbuf[i] = make_float2(__expf(e0), __expf(e1));
}

// ---------------- aggregation: one wave per node ----------------
// hfeat in bf16: lane loads one uint = 2 packed features. Lanes 0-31 cover
// head0 (features 0..63), lanes 32-63 head1 (features 64..127). Software-
// pipelined in chunks of 4 edges (next chunk's idx/w prefetched).
__global__ __launch_bounds__(256) void aggregate_kernel(
    const uint32* __restrict__ hfeat, const float2* __restrict__ wbuf,
    const int* __restrict__ rowptr, const int* __restrict__ csr_src,
    const float* __restrict__ bias, float* __restrict__ out, int nnodes)
{
  int n = (blockIdx.x * blockDim.x + threadIdx.x) >> 6;
  int lane = threadIdx.x & 63;
  if (n >= nnodes) return;
  int beg = rowptr[n], end = rowptr[n + 1];
  const bool hi = lane >= 32;
  float accE = 0.f, accO = 0.f, den = 0.f;

  int idxA[4]; float wA[4];
  int i = beg;
#pragma unroll
  for (int t = 0; t < 4; ++t) {
    int j = i + t;
    int jj = (j < end) ? j : beg;
    idxA[t] = csr_src[jj];
    float2 ww = wbuf[jj];
    float w = hi ? ww.y : ww.x;
    wA[t] = (j < end) ? w : 0.f;
  }
  i += 4;
  for (;;) {
    bool more = (i < end);
    int idxB[4]; float wB[4];
    if (more) {
#pragma unroll
      for (int t = 0; t < 4; ++t) {
        int j = i + t;
        int jj = (j < end) ? j : beg;
        idxB[t] = csr_src[jj];
        float2 ww = wbuf[jj];
        float w = hi ? ww.y : ww.x;
        wB[t] = (j < end) ? w : 0.f;
      }
    }
    uint32 hv[4];
#pragma unroll
    for (int t = 0; t < 4; ++t) hv[t] = hfeat[(size_t)idxA[t] * 64 + lane];
#pragma unroll
    for (int t = 0; t < 4; ++t) {
      float fe = __uint_as_float(hv[t] << 16);
      float fo = __uint_as_float(hv[t] & 0xFFFF0000u);
      accE = fmaf(wA[t], fe, accE);
      accO = fmaf(wA[t], fo, accO);
      den += wA[t];
    }
    if (!more) break;
#pragma unroll
    for (int t = 0; t < 4; ++t) { idxA[t] = idxB[t]; wA[t] = wB[t]; }
    i += 4;
  }
  float inv = 1.f / den;
  int m = lane & 31;
  int off = hi ? 64 : 0;
  float2 bb = *(const float2*)&bias[off + 2 * m];
  float v0 = accE * inv + bb.x;
  float v1 = accO * inv + bb.y;
  v0 = (v0 > 0.f) ? v0 : (__expf(v0) - 1.f);
  v1 = (v1 > 0.f) ? v1 : (__expf(v1) - 1.f);
  *(float2*)&out[(size_t)n * 128 + off + 2 * m] = make_float2(v0, v1);
}

// ---------------- final linear (256->40) + log_softmax, tiled GEMM ----------------
__global__ __launch_bounds__(256) void final_kernel(
    const float* __restrict__ h1, const float* __restrict__ h2,
    const float* __restrict__ lw, const float* __restrict__ lb,
    float* __restrict__ out, int nnodes)
{
  __shared__ __align__(16) float Hs[64][33];
  __shared__ __align__(16) float Ws2[32 * 40];
  const int tid = threadIdx.x;
  const int m = tid >> 2, q = tid & 3;
  const int n0 = blockIdx.x * 64;

  float bj[10];
#pragma unroll
  for (int j = 0; j < 10; ++j) bj[j] = lb[q * 10 + j];

  float acc[10];
#pragma unroll
  for (int j = 0; j < 10; ++j) acc[j] = 0.f;

  for (int kc = 0; kc < 256; kc += 32) {
    __syncthreads();
#pragma unroll
    for (int it = 0; it < 2; ++it) {
      int idx = tid + it * 256;
      int nd = idx >> 3, kk = (idx & 7) * 4;
      int n = n0 + nd;
      float4 v = make_float4(0.f, 0.f, 0.f, 0.f);
      if (n < nnodes) {
        const float* src = (kc < 128) ? &h1[(size_t)n * 128 + kc + kk]
                                      : &h2[(size_t)n * 128 + (kc - 128) + kk];
        v = *(const float4*)src;
      }
      Hs[nd][kk + 0] = v.x; Hs[nd][kk + 1] = v.y;
      Hs[nd][kk + 2] = v.z; Hs[nd][kk + 3] = v.w;
    }
    {
      float4 v = *(const float4*)&lw[kc * 40 + tid * 4];
      *(float4*)&Ws2[tid * 4] = v;
      if (tid < 64) {
        float4 v2 = *(const float4*)&lw[kc * 40 + (256 + tid) * 4];
        *(float4*)&Ws2[(256 + tid) * 4] = v2;
      }
    }
    __syncthreads();
#pragma unroll
    for (int k = 0; k < 32; ++k) {
      float a = Hs[m][k];
      const float* wr = &Ws2[k * 40 + q * 10];
#pragma unroll
      for (int j = 0; j < 10; ++j) acc[j] = fmaf(a, wr[j], acc[j]);
    }
  }

  float mx = -INFINITY;
#pragma unroll
  for (int j = 0; j < 10; ++j) { acc[j] += bj[j]; mx = fmaxf(mx, acc[j]); }
  mx = fmaxf(mx, __shfl_xor(mx, 1));
  mx = fmaxf(mx, __shfl_xor(mx, 2));
  float s = 0.f;
#pragma unroll
  for (int j = 0; j < 10; ++j) s += __expf(acc[j] - mx);
  s += __shfl_xor(s, 1);
  s += __shfl_xor(s, 2);
  float lg = mx + __logf(s);
  int n = n0 + m;
  if (n < nnodes) {
#pragma unroll
    for (int j = 0; j < 10; ++j) out[(size_t)n * 40 + q * 10 + j] = acc[j] - lg;
  }
}

// ---------------- launch ----------------

extern "C" void kernel_launch(void* const* d_in, const int* in_sizes, int n_in,
                              void* d_out, int out_size, void* d_ws, size_t ws_size,
                              hipStream_t stream) {
  const float* x   = (const float*)d_in[0];
  const int*   ei  = (const int*)d_in[1];
  const float* W0  = (const float*)d_in[2];
  const float* as0 = (const float*)d_in[3];
  const float* ad0 = (const float*)d_in[4];
  const float* b0  = (const float*)d_in[5];
  const float* W1  = (const float*)d_in[6];
  const float* as1 = (const float*)d_in[7];
  const float* ad1 = (const float*)d_in[8];
  const float* b1  = (const float*)d_in[9];
  const float* lw  = (const float*)d_in[10];
  const float* lb  = (const float*)d_in[11];
  float* out = (float*)d_out;

  char* p = (char*)d_ws;
  auto carve = [&](size_t bytes) { char* r = p; p += (bytes + 255) & ~(size_t)255; return r; };
  ushort16* hfeat = (ushort16*)carve((size_t)NN * 128 * 2);  // bf16
  float* h1o   = (float*)carve((size_t)NN * 128 * 4);
  float* h2o   = (float*)carve((size_t)NN * 128 * 4);
  float* es    = (float*)carve((size_t)NN * 2 * 4);
  float* ed    = (float*)carve((size_t)NN * 2 * 4);
  int* rowptr  = (int*)carve((size_t)(NN + 1) * 4);
  int* cnt     = (int*)carve((size_t)NN * 4);
  int* csr     = (int*)carve((size_t)ET * 4);
  int* csrd    = (int*)carve((size_t)ET * 4);
  float2* wbuf = (float2*)carve((size_t)ET * 8);
  int* bsum    = (int*)carve((size_t)NB * 4);
  int* boff    = (int*)carve((size_t)NB * 4);

  // CSR build (reused by both layers)
  zero_int_kernel<<<(NN + 1023) / 1024, 1024, 0, stream>>>(cnt, NN);
  count_kernel<<<(ET + 255) / 256, 256, 0, stream>>>(ei, cnt);
  scan_l1_kernel<<<NB, 256, 0, stream>>>(cnt, rowptr, bsum);
  scan_l2_kernel<<<1, 256, 0, stream>>>(bsum, boff, rowptr);
  scan_add_kernel<<<NB, 256, 0, stream>>>(rowptr, boff);
  zero_int_kernel<<<(NN + 1023) / 1024, 1024, 0, stream>>>(cnt, NN);
  scatter_kernel<<<(ET + 255) / 256, 256, 0, stream>>>(ei, rowptr, cnt, csr, csrd);

  // layer 1
  gemm_att_kernel<<<(NN + 63) / 64, 256, 0, stream>>>(x, W0, as0, ad0, hfeat, es, ed, NN);
  edge_w_kernel<<<(ET + 255) / 256, 256, 0, stream>>>(es, ed, csr, csrd, wbuf);
  aggregate_kernel<<<(NN * 64 + 255) / 256, 256, 0, stream>>>((const uint32*)hfeat, wbuf, rowptr, csr, b0, h1o, NN);
  // layer 2
  gemm_att_kernel<<<(NN + 63) / 64, 256, 0, stream>>>(h1o, W1, as1, ad1, hfeat, es, ed, NN);
  edge_w_kernel<<<(ET + 255) / 256, 256, 0, stream>>>(es, ed, csr, csrd, wbuf);
  aggregate_kernel<<<(NN * 64 + 255) / 256, 256, 0, stream>>>((const uint32*)hfeat, wbuf, rowptr, csr, b1, h2o, NN);
  // head
  final_kernel<<<(NN + 63) / 64, 256, 0, stream>>>(h1o, h2o, lw, lb, out, NN);
}